// Round 1
// baseline (693.915 us; speedup 1.0000x reference)
//
#include <hip/hip_runtime.h>

#define DEG 16
#define F_IN 128
#define H 32

__device__ __forceinline__ float relu_f(float x) { return fmaxf(x, 0.0f); }

// ---------------------------------------------------------------------------
// Kernel A0: Xn1[i] = relu((Asum[i]/D[i]) @ wn1p^T + bn1p + bn1s)
// Asum[i] = sum_j |X[i] - X[dst_ij]|  (X0 == zeros, so the self term is bias only)
// One block (128 threads) per node; thread t owns feature k=t.
// ---------------------------------------------------------------------------
__global__ __launch_bounds__(F_IN) void k_xn1(
    const float* __restrict__ X, const int* __restrict__ dst,
    const float* __restrict__ D,
    const float* __restrict__ wn1p, const float* __restrict__ bn1p,
    const float* __restrict__ bn1s,
    float* __restrict__ Xn1)
{
    const int i = blockIdx.x;
    const int t = threadIdx.x;
    __shared__ int ds[DEG];
    __shared__ float As[F_IN];
    if (t < DEG) ds[t] = dst[i * DEG + t];
    __syncthreads();
    const float xi = X[(size_t)i * F_IN + t];
    float s = 0.0f;
#pragma unroll
    for (int j = 0; j < DEG; ++j)
        s += fabsf(xi - X[(size_t)ds[j] * F_IN + t]);
    s *= (1.0f / D[i]);
    As[t] = s;
    __syncthreads();
    // 4 threads per output o; each covers 32 k's, then 2-step shuffle combine.
    const int o = t >> 2, q = t & 3;
    float p = 0.0f;
#pragma unroll
    for (int kk = 0; kk < 32; ++kk)
        p += As[q * 32 + kk] * wn1p[o * F_IN + q * 32 + kk];
    p += __shfl_xor(p, 1);
    p += __shfl_xor(p, 2);
    if (q == 0) Xn1[(size_t)i * H + o] = relu_f(p + bn1p[o] + bn1s[o]);
}

// ---------------------------------------------------------------------------
// Kernel A1: t1[e] = |X[src_e] - X[dst_e]| @ we1s^T    (E x 32, fp32)
// One thread per edge; we1s staged in LDS ([o][k] layout, broadcast reads).
// ---------------------------------------------------------------------------
__global__ __launch_bounds__(256) void k_t1(
    const float* __restrict__ X, const int* __restrict__ dst,
    const float* __restrict__ we1s,
    float* __restrict__ t1, long E)
{
    __shared__ float Ws[H * F_IN];  // 16 KiB
    const int tid = threadIdx.x;
#pragma unroll
    for (int r = 0; r < (H * F_IN) / 256; ++r)
        Ws[r * 256 + tid] = we1s[r * 256 + tid];
    __syncthreads();
    const long e = (long)blockIdx.x * 256 + tid;
    if (e >= E) return;
    const int i = (int)(e >> 4);   // src[e] == e/16 by construction
    const int d = dst[e];
    const float4* __restrict__ Xi4 = (const float4*)(X + (size_t)i * F_IN);
    const float4* __restrict__ Xd4 = (const float4*)(X + (size_t)d * F_IN);
    const float4* __restrict__ Ws4 = (const float4*)Ws;
    float acc[H];
#pragma unroll
    for (int o = 0; o < H; ++o) acc[o] = 0.0f;
    for (int c = 0; c < F_IN / 4; ++c) {
        const float4 xi = Xi4[c];
        const float4 xd = Xd4[c];
        const float a0 = fabsf(xi.x - xd.x);
        const float a1 = fabsf(xi.y - xd.y);
        const float a2 = fabsf(xi.z - xd.z);
        const float a3 = fabsf(xi.w - xd.w);
#pragma unroll
        for (int o = 0; o < H; ++o) {
            const float4 w = Ws4[o * (F_IN / 4) + c];
            acc[o] += a0 * w.x + a1 * w.y + a2 * w.z + a3 * w.w;
        }
    }
    float4* __restrict__ T4 = (float4*)(t1 + (size_t)e * H);
#pragma unroll
    for (int oc = 0; oc < H / 4; ++oc)
        T4[oc] = make_float4(acc[4 * oc], acc[4 * oc + 1], acc[4 * oc + 2], acc[4 * oc + 3]);
}

// ---------------------------------------------------------------------------
// Kernel B: vals1[e] = relu(Ef1 @ we1p^T + be1p + t1[e] + be1s)   (in-place on t1)
//           Xn2[i]  = relu((sum_e vals1 / D) @ wn2p^T + bn2p + Xn1 @ wn2s^T + bn2s)
// Ef1 concat folded: Ef@W^T = x1@Wa^T + x2@Wb^T with Wa=0.5(W1+W2), Wb=0.5(W2-W1).
// Node reduction via 16-lane shuffle butterfly (node's edges are one lane group).
// ---------------------------------------------------------------------------
__global__ __launch_bounds__(256) void k_edge1_xn2(
    const float* __restrict__ Xn1, const int* __restrict__ dst,
    const float* __restrict__ D,
    const float* __restrict__ we1p, const float* __restrict__ be1p,
    const float* __restrict__ be1s,
    const float* __restrict__ wn2p, const float* __restrict__ bn2p,
    const float* __restrict__ wn2s, const float* __restrict__ bn2s,
    float* __restrict__ t1v1, float* __restrict__ Xn2, long E)
{
    __shared__ float Wa[H * H], Wb[H * H];   // folded we1p
    __shared__ float W2p[H * H], W2s[H * H]; // wn2p, wn2s
    __shared__ float b1[H], b2[H];
    const int tid = threadIdx.x;
#pragma unroll
    for (int r = 0; r < (H * H) / 256; ++r) {
        const int idx = r * 256 + tid;
        const int o = idx >> 5, k = idx & 31;
        const float w1 = we1p[o * 2 * H + k];
        const float w2 = we1p[o * 2 * H + H + k];
        Wa[idx] = 0.5f * (w1 + w2);
        Wb[idx] = 0.5f * (w2 - w1);
        W2p[idx] = wn2p[idx];
        W2s[idx] = wn2s[idx];
    }
    if (tid < H) { b1[tid] = be1p[tid] + be1s[tid]; b2[tid] = bn2p[tid] + bn2s[tid]; }
    __syncthreads();
    const long e = (long)blockIdx.x * 256 + tid;
    if (e >= E) return;
    const int i = (int)(e >> 4);
    const int d = dst[e];
    float x1[H], x2[H];
    {
        const float4* p1 = (const float4*)(Xn1 + (size_t)i * H);
        const float4* p2 = (const float4*)(Xn1 + (size_t)d * H);
#pragma unroll
        for (int c = 0; c < H / 4; ++c) {
            float4 v = p1[c]; x1[4*c]=v.x; x1[4*c+1]=v.y; x1[4*c+2]=v.z; x1[4*c+3]=v.w;
            float4 u = p2[c]; x2[4*c]=u.x; x2[4*c+1]=u.y; x2[4*c+2]=u.z; x2[4*c+3]=u.w;
        }
    }
    float acc[H];
    {
        const float4* T4 = (const float4*)(t1v1 + (size_t)e * H);
#pragma unroll
        for (int c = 0; c < H / 4; ++c) {
            float4 v = T4[c];
            acc[4*c]   = v.x + b1[4*c];
            acc[4*c+1] = v.y + b1[4*c+1];
            acc[4*c+2] = v.z + b1[4*c+2];
            acc[4*c+3] = v.w + b1[4*c+3];
        }
    }
#pragma unroll
    for (int o = 0; o < H; ++o) {
        float s = 0.0f;
#pragma unroll
        for (int k = 0; k < H; ++k)
            s += x1[k] * Wa[o * H + k] + x2[k] * Wb[o * H + k];
        acc[o] = relu_f(acc[o] + s);
    }
    {   // store vals1 in place over t1
        float4* T4 = (float4*)(t1v1 + (size_t)e * H);
#pragma unroll
        for (int c = 0; c < H / 4; ++c)
            T4[c] = make_float4(acc[4*c], acc[4*c+1], acc[4*c+2], acc[4*c+3]);
    }
    // butterfly sum over the node's 16 lanes (reuse acc as the reduction buffer)
#pragma unroll
    for (int m = 1; m < DEG; m <<= 1) {
#pragma unroll
        for (int o = 0; o < H; ++o)
            acc[o] += __shfl_xor(acc[o], m);
    }
    const float invD = 1.0f / D[i];
#pragma unroll
    for (int o = 0; o < H; ++o) acc[o] *= invD;
    const int lane = tid & (DEG - 1);
#pragma unroll
    for (int rep = 0; rep < 2; ++rep) {
        const int o = lane + rep * DEG;
        float a2 = b2[o];
#pragma unroll
        for (int k = 0; k < H; ++k)
            a2 += acc[k] * W2p[o * H + k] + x1[k] * W2s[o * H + k];
        Xn2[(size_t)i * H + o] = relu_f(a2);
    }
}

// ---------------------------------------------------------------------------
// Kernel C: vals2 = relu(Ef2 @ we2p^T + be2p + vals1 @ we2s^T + be2s)
//           out[e] = sigmoid(vals2 @ wc^T + bc)
// ---------------------------------------------------------------------------
__global__ __launch_bounds__(256) void k_edge2_out(
    const float* __restrict__ Xn2, const int* __restrict__ dst,
    const float* __restrict__ we2p, const float* __restrict__ be2p,
    const float* __restrict__ we2s, const float* __restrict__ be2s,
    const float* __restrict__ wc, const float* __restrict__ bc,
    const float* __restrict__ vals1, float* __restrict__ out, long E)
{
    __shared__ float Wa[H * H], Wb[H * H], Ws[H * H];
    __shared__ float b[H], wcl[H];
    const int tid = threadIdx.x;
#pragma unroll
    for (int r = 0; r < (H * H) / 256; ++r) {
        const int idx = r * 256 + tid;
        const int o = idx >> 5, k = idx & 31;
        const float w1 = we2p[o * 2 * H + k];
        const float w2 = we2p[o * 2 * H + H + k];
        Wa[idx] = 0.5f * (w1 + w2);
        Wb[idx] = 0.5f * (w2 - w1);
        Ws[idx] = we2s[idx];
    }
    if (tid < H) { b[tid] = be2p[tid] + be2s[tid]; wcl[tid] = wc[tid]; }
    __syncthreads();
    const long e = (long)blockIdx.x * 256 + tid;
    if (e >= E) return;
    const int i = (int)(e >> 4);
    const int d = dst[e];
    float x1[H], x2[H], v1[H];
    {
        const float4* p1 = (const float4*)(Xn2 + (size_t)i * H);
        const float4* p2 = (const float4*)(Xn2 + (size_t)d * H);
        const float4* pv = (const float4*)(vals1 + (size_t)e * H);
#pragma unroll
        for (int c = 0; c < H / 4; ++c) {
            float4 v = p1[c]; x1[4*c]=v.x; x1[4*c+1]=v.y; x1[4*c+2]=v.z; x1[4*c+3]=v.w;
            float4 u = p2[c]; x2[4*c]=u.x; x2[4*c+1]=u.y; x2[4*c+2]=u.z; x2[4*c+3]=u.w;
            float4 w = pv[c]; v1[4*c]=w.x; v1[4*c+1]=w.y; v1[4*c+2]=w.z; v1[4*c+3]=w.w;
        }
    }
    float sx = 0.0f;
#pragma unroll
    for (int o = 0; o < H; ++o) {
        float s = b[o];
#pragma unroll
        for (int k = 0; k < H; ++k)
            s += v1[k] * Ws[o * H + k] + x1[k] * Wa[o * H + k] + x2[k] * Wb[o * H + k];
        sx += relu_f(s) * wcl[o];
    }
    out[e] = 1.0f / (1.0f + __expf(-(sx + bc[0])));
}

// ---------------------------------------------------------------------------
extern "C" void kernel_launch(void* const* d_in, const int* in_sizes, int n_in,
                              void* d_out, int out_size, void* d_ws, size_t ws_size,
                              hipStream_t stream)
{
    const float* X    = (const float*)d_in[0];
    const int*   dst  = (const int*)  d_in[2];
    const float* D    = (const float*)d_in[3];
    const float* wn1p = (const float*)d_in[4];
    const float* bn1p = (const float*)d_in[5];
    // d_in[6] = wn1s is unused: X0 == zeros, self term reduces to bn1s.
    const float* bn1s = (const float*)d_in[7];
    const float* we1p = (const float*)d_in[8];
    const float* be1p = (const float*)d_in[9];
    const float* we1s = (const float*)d_in[10];
    const float* be1s = (const float*)d_in[11];
    const float* wn2p = (const float*)d_in[12];
    const float* bn2p = (const float*)d_in[13];
    const float* wn2s = (const float*)d_in[14];
    const float* bn2s = (const float*)d_in[15];
    const float* we2p = (const float*)d_in[16];
    const float* be2p = (const float*)d_in[17];
    const float* we2s = (const float*)d_in[18];
    const float* be2s = (const float*)d_in[19];
    const float* wc   = (const float*)d_in[20];
    const float* bc   = (const float*)d_in[21];

    const int  N = in_sizes[3];      // D has one entry per node
    const long E = in_sizes[1];      // src has one entry per edge

    // workspace: [t1/vals1 : E*H] [Xn1 : N*H] [Xn2 : N*H]  (fp32)
    float* t1v1 = (float*)d_ws;
    float* Xn1  = t1v1 + (size_t)E * H;
    float* Xn2  = Xn1 + (size_t)N * H;
    float* outp = (float*)d_out;

    const int eb = (int)((E + 255) / 256);

    k_xn1<<<N, F_IN, 0, stream>>>(X, dst, D, wn1p, bn1p, bn1s, Xn1);
    k_t1<<<eb, 256, 0, stream>>>(X, dst, we1s, t1v1, E);
    k_edge1_xn2<<<eb, 256, 0, stream>>>(Xn1, dst, D, we1p, be1p, be1s,
                                        wn2p, bn2p, wn2s, bn2s, t1v1, Xn2, E);
    k_edge2_out<<<eb, 256, 0, stream>>>(Xn2, dst, we2p, be2p, we2s, be2s,
                                        wc, bc, t1v1, outp, E);
}